// Round 12
// baseline (163.199 us; speedup 1.0000x reference)
//
#include <hip/hip_runtime.h>
#include <math.h>

#define BB 256
#define SSEQ 128
#define INPUT 256
#define PD 128
#define EE 64
#define RW 256
#define MM 512
#define WW 64
#define KD 384          // IN_DIM

typedef _Float16 half8 __attribute__((ext_vector_type(8)));
typedef __fp16 fp16x2 __attribute__((ext_vector_type(2)));
typedef float float4v __attribute__((ext_vector_type(4)));
typedef float f32x16 __attribute__((ext_vector_type(16)));
typedef unsigned int uint2v __attribute__((ext_vector_type(2)));

#define LOG2E 1.44269504088896f
#define OUT1 8388608u

// LDS byte layout (R3 map).
// Phase A (prologue): [0,128K) = Wq x-part f16 image, chunk c = (k>>3)*256 + n.
// Phase B (flash):    [0,64K)  = mem f16 rows (chunk m*8 + (c^(m&7))),
//                     [64K,128K) = memT f16 (chunk w*64 + (cm^(w&7))).
// [128K, 128K+6K) f32 scratch.
#define MEMT16   4096            // memT base in uint4 units (64K/16)
#define F32_OFF  131072
#define LDS_BYTES (131072 + 6144)
#define UE_O 0
#define PE_O 64
#define QPE_O 192
#define QP_O 448                  // qpart [1024]

union H8 { half8 h8; unsigned int u[4]; uint4 u4; };

__device__ __forceinline__ unsigned int pk2(float a, float b) {
    union { fp16x2 h; unsigned int u; } p;
    p.h = __builtin_amdgcn_cvt_pkrtz(a, b);
    return p.u;
}

// v_permlane32_swap_b32 via the builtin (NOT inline asm: two "+v" asm operands
// holding the same value can be coalesced into ONE physical VGPR -> self-swap
// garbage. That was R1's absmax=4.6e7 failure.)
// returns r[0] = [a_lo | b_lo], r[1] = [a_hi | b_hi]
__device__ __forceinline__ float xhalf_max(float v) {
    uint2v r = __builtin_amdgcn_permlane32_swap(__float_as_uint(v), __float_as_uint(v), false, false);
    return fmaxf(__uint_as_float(r[0]), __uint_as_float(r[1]));
}
__device__ __forceinline__ float xhalf_sum(float v) {
    uint2v r = __builtin_amdgcn_permlane32_swap(__float_as_uint(v), __float_as_uint(v), false, false);
    return __uint_as_float(r[0]) + __uint_as_float(r[1]);
}

// ---------- single fused kernel: 256 blocks x 1024 threads (16 waves) ----------
// HARD-WON CONSTRAINTS (do not violate):
//  * launch_bounds (1024,4): 4 waves/SIMD -> 128 unified regs/wave. The flash
//    loop uses EXACTLY that (64 arch + ~64 acc). ANY extra live state across
//    the flash loop spills or degrades codegen globally -- R5 (mtile pairing,
//    +26MB spill), R9/R10 (straggler-kill ws pointers + dual loop copies:
//    uniform 1.8x slowdown at unchanged VGPR_Count=64). Even a few extra live
//    pointer VGPRs tip it. (1024,8) needs <=64 regs: impossible.
//  * NO barriers inside phase Q or the flash loop (R6: +8.5us).
//  * NO conditional global-store path in the flash loop, and NO extra kernel
//    args / derived pointers live across it (R9/R10).
//  * No multi-pass restructure of the flash loop (old-R8: spills, 4x slower).
//  * Flash body: 32x32x16 swapped-operand, permlane-only cross-lane, defer-max
//    THR=8, QK-frag prefetch, setprio, per-sq rotation+sleep desync (R7, -3%).
// R12 (schedule-only edits, zero extra live state):
//  (a) PV MFMA interleave Oa0,Oa1,Oa0,Oa1 (was Oa0,Oa0,Oa1,Oa1) -- two
//      interleaved 2-deep chains instead of two serial ones.
//  (b) deeper sleep stagger 5/10/15 (was 2/4/6) -- spread co-resident waves
//      across a full mtile phase (~1.6K cyc), not a quarter.
__global__ void __launch_bounds__(1024, 4)
attn_kernel(const float* __restrict__ x, const int* __restrict__ user_id,
            const float* __restrict__ uet, const float* __restrict__ W_proc,
            const float* __restrict__ b_proc, const float* __restrict__ Wq,
            const float* __restrict__ memG, float* __restrict__ out)
{
    extern __shared__ char smraw[];
    unsigned short* smemu = (unsigned short*)smraw;
    unsigned int*   smw   = (unsigned int*)smraw;
    uint4*          sm128 = (uint4*)smraw;
    float*          smf   = (float*)(smraw + F32_OFF);

    const int t = threadIdx.x;
    const int b = blockIdx.x;
    const int lane = t & 63, wv = t >> 6;        // 16 waves
    const int n16 = lane & 15, quad = lane >> 4;
    const int l31 = lane & 31, hh = lane >> 5;
    const int r = wv & 3, sq = wv >> 2;          // sq 0..3
    const int s0 = sq * 32;
    const int mswz = l31 & 7;

    const int uid = user_id[b];
    const int sid = uid & 15;
    const float* memB = memG + (size_t)sid * (MM*WW);
    const float* wqX  = Wq + (size_t)sid * KD * RW;

    if (t < EE) smf[UE_O + t] = uet[(size_t)uid*EE + t];

    // ---- Prologue A: Wq x-part -> LDS f16 image [k/8][n][k%8], unrolled x4 ----
    {
        const int n = t & 255, h = t >> 8;       // n fixed per thread
        for (int i = 0; i < 32; i += 4) {
            float w[8];
            #pragma unroll
            for (int j = 0; j < 4; ++j) {
                int kp = (i + j)*4 + h;
                w[2*j]   = wqX[(size_t)(2*kp)    *RW + n];
                w[2*j+1] = wqX[(size_t)(2*kp + 1)*RW + n];
            }
            #pragma unroll
            for (int j = 0; j < 4; ++j) {
                int kp = (i + j)*4 + h;
                smw[((((kp>>2)*256 + n) << 2) | (kp & 3))] = pk2(w[2*j], w[2*j+1]);
            }
        }
    }
    __syncthreads();

    // pe
    if (t < PD) {
        float a = b_proc[t];
        #pragma unroll
        for (int e = 0; e < EE; ++e) a = fmaf(smf[UE_O + e], W_proc[e*PD + t], a);
        smf[PE_O + t] = a;
    }
    __syncthreads();
    // qpe partials: 4 independent chains so the 32 loads can hoist
    {
        int n = t & 255, h = t >> 8;
        const float* wr = wqX + (size_t)(256 + h*32)*RW + n;
        float sa = 0.f, sb = 0.f, sc = 0.f, sd = 0.f;
        #pragma unroll
        for (int k = 0; k < 32; k += 4) {
            sa = fmaf(smf[PE_O + h*32 + k],     wr[(size_t)(k)*RW],     sa);
            sb = fmaf(smf[PE_O + h*32 + k + 1], wr[(size_t)(k + 1)*RW], sb);
            sc = fmaf(smf[PE_O + h*32 + k + 2], wr[(size_t)(k + 2)*RW], sc);
            sd = fmaf(smf[PE_O + h*32 + k + 3], wr[(size_t)(k + 3)*RW], sd);
        }
        smf[QP_O + h*256 + n] = (sa + sb) + (sc + sd);
    }
    __syncthreads();
    if (t < 256) smf[QPE_O + t] = LOG2E * (smf[QP_O + t] + smf[QP_O + 256 + t]
                                         + smf[QP_O + 512 + t] + smf[QP_O + 768 + t]);
    __syncthreads();

    // ---- Phase Q (x-part k<256 only; pe via qpe bias; kc MUST stop at 8) ----
    float4v qacc[4][2];
    #pragma unroll
    for (int mt = 0; mt < 4; ++mt)
        #pragma unroll
        for (int nt = 0; nt < 2; ++nt) qacc[mt][nt] = (float4v)0.f;

    const float* xB = x + (size_t)(b*SSEQ + s0) * INPUT;
    for (int kc = 0; kc < 8; ++kc) {
        H8 afr[4];
        #pragma unroll
        for (int mt = 0; mt < 4; ++mt)
            afr[mt].u4 = sm128[(kc*4 + quad)*256 + r*64 + mt*16 + n16];
        H8 bfr[2];
        #pragma unroll
        for (int nt = 0; nt < 2; ++nt) {
            const float* xg = xB + (size_t)(nt*16 + n16)*INPUT + kc*32 + quad*8;
            float4 a0 = *(const float4*)xg;
            float4 a1 = *(const float4*)(xg + 4);
            bfr[nt].u[0] = pk2(a0.x*LOG2E, a0.y*LOG2E);
            bfr[nt].u[1] = pk2(a0.z*LOG2E, a0.w*LOG2E);
            bfr[nt].u[2] = pk2(a1.x*LOG2E, a1.y*LOG2E);
            bfr[nt].u[3] = pk2(a1.z*LOG2E, a1.w*LOG2E);
        }
        __builtin_amdgcn_s_setprio(1);
        #pragma unroll
        for (int mt = 0; mt < 4; ++mt)
            #pragma unroll
            for (int nt = 0; nt < 2; ++nt)
                qacc[mt][nt] = __builtin_amdgcn_mfma_f32_16x16x32_f16(afr[mt].h8, bfr[nt].h8, qacc[mt][nt], 0, 0, 0);
        __builtin_amdgcn_s_setprio(0);
    }
    #pragma unroll
    for (int mt = 0; mt < 4; ++mt)
        #pragma unroll
        for (int reg = 0; reg < 4; ++reg) {
            float qv = smf[QPE_O + r*64 + mt*16 + quad*4 + reg];
            #pragma unroll
            for (int nt = 0; nt < 2; ++nt) qacc[mt][nt][reg] += qv;
        }
    unsigned int pkq[4][2][2];
    #pragma unroll
    for (int mt = 0; mt < 4; ++mt)
        #pragma unroll
        for (int nt = 0; nt < 2; ++nt) {
            pkq[mt][nt][0] = pk2(qacc[mt][nt][0], qacc[mt][nt][1]);
            pkq[mt][nt][1] = pk2(qacc[mt][nt][2], qacc[mt][nt][3]);
        }
    // ---- repack q into 32x32x16 B-operand layout (one-time) ----
    H8 bqf[4];
    {
        const int ntSel = (lane >> 4) & 1;           // = bit4 of s5
        const int srcBase = (lane & 15) + (lane & 32);
        #pragma unroll
        for (int kc = 0; kc < 4; ++kc)
            #pragma unroll
            for (int jp = 0; jp < 4; ++jp) {
                const int src = srcBase + ((jp >> 1) << 4);
                int v0 = __shfl((int)pkq[kc][0][jp & 1], src, 64);
                int v1 = __shfl((int)pkq[kc][1][jp & 1], src, 64);
                bqf[kc].u[jp] = (unsigned int)(ntSel ? v1 : v0);
            }
    }
    __syncthreads();                             // all waves done reading Wq image

    // ---- Prologue B: overwrite LDS with mem f16 images (convert + transpose) ----
    for (int i = 0; i < 4; ++i) {
        int id = t + i*1024;
        int m = id >> 3, cw = id & 7;
        const float* g = memB + m*64 + cw*8;
        float4 a0 = *(const float4*)g;
        float4 a1 = *(const float4*)(g + 4);
        sm128[m*8 + (cw ^ (m & 7))] =
            make_uint4(pk2(a0.x,a0.y), pk2(a0.z,a0.w), pk2(a1.x,a1.y), pk2(a1.z,a1.w));
    }
    __syncthreads();
    for (int i = 0; i < 4; ++i) {
        int id = t + i*1024;
        int w = id & 63, cm = id >> 6;
        unsigned int uu[4];
        #pragma unroll
        for (int p = 0; p < 4; ++p) {
            int m0 = cm*8 + 2*p, m1 = m0 + 1;
            unsigned short lo = smemu[m0*64 + (((w>>3) ^ (m0&7))<<3) + (w&7)];
            unsigned short hi = smemu[m1*64 + (((w>>3) ^ (m1&7))<<3) + (w&7)];
            uu[p] = (unsigned int)lo | ((unsigned int)hi << 16);
        }
        sm128[MEMT16 + w*64 + (cm ^ (w & 7))] = make_uint4(uu[0],uu[1],uu[2],uu[3]);
    }
    __syncthreads();

    // ========== single-pass flash loop: rotated + staggered per sq ==========
    // Online softmax is tile-order-invariant: each sq-group starts at mtile
    // sq*4 and wraps. Co-resident waves on a SIMD (same wv&3, sq=0..3) are
    // additionally offset by a one-time s_sleep so their phases interleave.
    if (sq == 1) __builtin_amdgcn_s_sleep(5);
    else if (sq == 2) __builtin_amdgcn_s_sleep(10);
    else if (sq == 3) __builtin_amdgcn_s_sleep(15);

    f32x16 Oa0 = (f32x16)0.f, Oa1 = (f32x16)0.f;
    float Ml = -1e30f, llp = 0.f;
    const int mt0 = sq * 4;

    H8 afc[4];
    #pragma unroll
    for (int kc = 0; kc < 4; ++kc)
        afc[kc].u4 = sm128[(mt0*32 + l31)*8 + (((kc<<1) + hh) ^ mswz)];

    for (int i = 0; i < 16; ++i) {
        const int mtile = (i + mt0) & 15;
        f32x16 Sa = (f32x16)0.f;
        __builtin_amdgcn_s_setprio(1);
        #pragma unroll
        for (int kc = 0; kc < 4; ++kc)
            Sa = __builtin_amdgcn_mfma_f32_32x32x16_f16(afc[kc].h8, bqf[kc].h8, Sa, 0, 0, 0);
        __builtin_amdgcn_s_setprio(0);
        if (i < 15) {
            const int mrow = ((i + 1 + mt0) & 15)*32 + l31;
            #pragma unroll
            for (int kc = 0; kc < 4; ++kc)
                afc[kc].u4 = sm128[mrow*8 + (((kc<<1) + hh) ^ mswz)];
        }
        const int c0 = mtile*4 + hh;
        H8 afP0, afP1, afP2, afP3;
        afP0.u4 = sm128[MEMT16 + l31*64        + ( c0      ^ mswz)];
        afP1.u4 = sm128[MEMT16 + l31*64        + ((c0 + 2) ^ mswz)];
        afP2.u4 = sm128[MEMT16 + (32 + l31)*64 + ( c0      ^ mswz)];
        afP3.u4 = sm128[MEMT16 + (32 + l31)*64 + ((c0 + 2) ^ mswz)];
        float m0 = fmaxf(fmaxf(Sa[0], Sa[1]), Sa[2]);
        float m1 = fmaxf(fmaxf(Sa[3], Sa[4]), Sa[5]);
        float m2 = fmaxf(fmaxf(Sa[6], Sa[7]), Sa[8]);
        float m3 = fmaxf(fmaxf(Sa[9], Sa[10]), Sa[11]);
        float m4 = fmaxf(fmaxf(Sa[12], Sa[13]), Sa[14]);
        float m5 = fmaxf(fmaxf(m0, m1), Sa[15]);
        float m6 = fmaxf(fmaxf(m2, m3), m4);
        float tmx = xhalf_max(fmaxf(m5, m6));
        // defer-max (T13): rescale only when running max grows by > 8 (log2).
        if (__any(tmx > Ml + 8.0f)) {
            float Mn = fmaxf(Ml, tmx);
            float al = __builtin_amdgcn_exp2f(Ml - Mn);
            Ml = Mn;
            llp *= al;
            #pragma unroll
            for (int g = 0; g < 16; ++g) { Oa0[g] *= al; Oa1[g] *= al; }
        }
        float pv[16];
        #pragma unroll
        for (int g = 0; g < 16; ++g) pv[g] = __builtin_amdgcn_exp2f(Sa[g] - Ml);
        float ts = (((pv[0]+pv[1])+(pv[2]+pv[3])) + ((pv[4]+pv[5])+(pv[6]+pv[7])))
                 + (((pv[8]+pv[9])+(pv[10]+pv[11])) + ((pv[12]+pv[13])+(pv[14]+pv[15])));
        llp += ts;
        uint2v rA0 = __builtin_amdgcn_permlane32_swap(pk2(pv[0],pv[1]),   pk2(pv[4],pv[5]),   false, false);
        uint2v rB0 = __builtin_amdgcn_permlane32_swap(pk2(pv[2],pv[3]),   pk2(pv[6],pv[7]),   false, false);
        uint2v rA1 = __builtin_amdgcn_permlane32_swap(pk2(pv[8],pv[9]),   pk2(pv[12],pv[13]), false, false);
        uint2v rB1 = __builtin_amdgcn_permlane32_swap(pk2(pv[10],pv[11]), pk2(pv[14],pv[15]), false, false);
        H8 bp0; bp0.u[0]=rA0[0]; bp0.u[1]=rB0[0]; bp0.u[2]=rA0[1]; bp0.u[3]=rB0[1];
        H8 bp1; bp1.u[0]=rA1[0]; bp1.u[1]=rB1[0]; bp1.u[2]=rA1[1]; bp1.u[3]=rB1[1];
        // PV: interleave the two accumulator chains (R12a) -- second MFMA of
        // each pair never waits on the first's accumulator.
        __builtin_amdgcn_s_setprio(1);
        Oa0 = __builtin_amdgcn_mfma_f32_32x32x16_f16(afP0.h8, bp0.h8, Oa0, 0, 0, 0);
        Oa1 = __builtin_amdgcn_mfma_f32_32x32x16_f16(afP2.h8, bp0.h8, Oa1, 0, 0, 0);
        Oa0 = __builtin_amdgcn_mfma_f32_32x32x16_f16(afP1.h8, bp1.h8, Oa0, 0, 0, 0);
        Oa1 = __builtin_amdgcn_mfma_f32_32x32x16_f16(afP3.h8, bp1.h8, Oa1, 0, 0, 0);
        __builtin_amdgcn_s_setprio(0);
    }

    // combine the two half-partials of the denominator (lane <-> lane^32)
    float inv = 1.0f / xhalf_sum(llp);

    // ---- store read_words ----
    {
        const int s = s0 + l31;
        float* op = out + ((size_t)(b*SSEQ + s)*4 + r)*WW;
        #pragma unroll
        for (int rq = 0; rq < 4; ++rq) {
            float4 o0 = make_float4(Oa0[rq*4+0]*inv, Oa0[rq*4+1]*inv,
                                    Oa0[rq*4+2]*inv, Oa0[rq*4+3]*inv);
            *(float4*)&op[rq*8 + hh*4] = o0;
            float4 o1 = make_float4(Oa1[rq*4+0]*inv, Oa1[rq*4+1]*inv,
                                    Oa1[rq*4+2]*inv, Oa1[rq*4+3]*inv);
            *(float4*)&op[32 + rq*8 + hh*4] = o1;
        }
    }

    // ---- final_state (b == 255): recompute scores, store normalized wts ----
    if (b == BB - 1) {
        const int s = s0 + l31;
        size_t base = (size_t)OUT1 + ((size_t)(s*4 + r) << 9);
        for (int mtile = 0; mtile < 16; ++mtile) {
            f32x16 Sa = (f32x16)0.f;
            const int mrow = mtile*32 + l31;
            #pragma unroll
            for (int kc = 0; kc < 4; ++kc) {
                H8 af; af.u4 = sm128[mrow*8 + (((kc<<1) + hh) ^ mswz)];
                Sa = __builtin_amdgcn_mfma_f32_32x32x16_f16(af.h8, bqf[kc].h8, Sa, 0, 0, 0);
            }
            #pragma unroll
            for (int rq = 0; rq < 4; ++rq) {
                float4 w4 = make_float4(
                    __builtin_amdgcn_exp2f(Sa[rq*4+0] - Ml) * inv,
                    __builtin_amdgcn_exp2f(Sa[rq*4+1] - Ml) * inv,
                    __builtin_amdgcn_exp2f(Sa[rq*4+2] - Ml) * inv,
                    __builtin_amdgcn_exp2f(Sa[rq*4+3] - Ml) * inv);
                *(float4*)&out[base + mtile*32 + rq*8 + hh*4] = w4;
            }
        }
    }
}

extern "C" void kernel_launch(void* const* d_in, const int* in_sizes, int n_in,
                              void* d_out, int out_size, void* d_ws, size_t ws_size,
                              hipStream_t stream) {
    const float* x    = (const float*)d_in[0];
    const int*   uid  = (const int*)  d_in[1];
    const float* uet  = (const float*)d_in[2];
    const float* Wp   = (const float*)d_in[3];
    const float* bp   = (const float*)d_in[4];
    const float* Wq   = (const float*)d_in[5];
    const float* mem  = (const float*)d_in[6];
    float* out = (float*)d_out;

    (void)hipFuncSetAttribute((const void*)attn_kernel,
                              hipFuncAttributeMaxDynamicSharedMemorySize, LDS_BYTES);
    attn_kernel<<<BB, 1024, LDS_BYTES, stream>>>(x, uid, uet, Wp, bp, Wq, mem, out);
}